// Round 6
// baseline (839.593 us; speedup 1.0000x reference)
//
#include <hip/hip_runtime.h>

#define NN 100000
#define NE 1600000
#define NG 64
#define NBUK 1021     // ceil(NN/BPB)
#define BPB  98       // nodes per bucket
#define GPART 128     // partition grid

using bf16x8 = __attribute__((ext_vector_type(8))) short;
using f32x4  = __attribute__((ext_vector_type(4))) float;

__device__ inline unsigned short f2bf(float f){
    union { float f; unsigned u; } v; v.f = f;
    unsigned r = (v.u + 0x7FFFu + ((v.u >> 16) & 1u)) >> 16;
    return (unsigned short)r;
}

// ---------------- zero (pooled only) ----------------
__global__ void k_zero(float* p, int n){
    int i = blockIdx.x*blockDim.x + threadIdx.x;
    if (i < n) p[i] = 0.f;
}

// ---------------- W1 -> bf16, fragment-ordered ----------------
__global__ __launch_bounds__(256) void k_prepw(const float* __restrict__ W1, short* __restrict__ Wb){
    int i = blockIdx.x*256 + threadIdx.x;
    if (i < 512*64){
        int k = i >> 6, c = i & 63;
        int g = k >> 5, r = k & 31, s = r >> 3, j = r & 7;
        Wb[(((g*4+s)*64 + c) << 3) + j] = (short)f2bf(W1[i]);
    }
}

// ---------------- phase A: per-block bucket histograms (LDS atomics, coalesced stores) ----------------
__global__ __launch_bounds__(256) void k_count(const int* __restrict__ src, const int* __restrict__ dst,
                                               int* __restrict__ cntD, int* __restrict__ cntS, int E){
    __shared__ int hD[1024], hS[1024];
    for (int i=threadIdx.x; i<1024; i+=256){ hD[i]=0; hS[i]=0; }
    __syncthreads();
    int chunk = (E + GPART - 1)/GPART;
    int start = blockIdx.x*chunk;
    int end   = min(E, start + chunk);
    for (int e = start + threadIdx.x; e < end; e += 256){
        atomicAdd(&hS[src[e]/BPB], 1);
        atomicAdd(&hD[dst[e]/BPB], 1);
    }
    __syncthreads();
    for (int i=threadIdx.x; i<1024; i+=256){
        cntD[blockIdx.x*1024 + i] = hD[i];
        cntS[blockIdx.x*1024 + i] = hS[i];
    }
}

// ---------------- scan A: per-bucket totals ----------------
__global__ __launch_bounds__(256) void k_scanA(const int* __restrict__ cntD, const int* __restrict__ cntS,
                                               int* __restrict__ totD, int* __restrict__ totS){
    int t = blockIdx.x*256 + threadIdx.x;   // grid 4 -> t in [0,1024)
    int sD=0, sS=0;
    for (int b=0;b<GPART;b++){ sD += cntD[b*1024+t]; sS += cntS[b*1024+t]; }
    totD[t]=sD; totS[t]=sS;
}

// ---------------- scan B: exclusive scan of bucket totals ----------------
__global__ __launch_bounds__(1024) void k_scanB(const int* __restrict__ totD, const int* __restrict__ totS,
                                                int* __restrict__ bstartD, int* __restrict__ bstartS){
    __shared__ int sd[1024];
    int t = threadIdx.x;
    int v = totD[t];
    sd[t] = v; __syncthreads();
    for (int off=1; off<1024; off<<=1){
        int tv = (t >= off) ? sd[t-off] : 0;
        __syncthreads();
        sd[t] += tv;
        __syncthreads();
    }
    if (t==0) bstartD[0]=0;
    if (t < NBUK) bstartD[t+1] = sd[t];
    __syncthreads();
    v = totS[t];
    sd[t] = v; __syncthreads();
    for (int off=1; off<1024; off<<=1){
        int tv = (t >= off) ? sd[t-off] : 0;
        __syncthreads();
        sd[t] += tv;
        __syncthreads();
    }
    if (t==0) bstartS[0]=0;
    if (t < NBUK) bstartS[t+1] = sd[t];
}

// ---------------- scan C: cnt arrays -> absolute per-(block,bucket) starts ----------------
__global__ __launch_bounds__(256) void k_scanC(int* __restrict__ cntD, int* __restrict__ cntS,
                                               const int* __restrict__ bstartD, const int* __restrict__ bstartS){
    int t = blockIdx.x*256 + threadIdx.x;
    if (t < NBUK){
        int rD = bstartD[t], rS = bstartS[t];
        for (int b=0;b<GPART;b++){
            int idx = b*1024 + t;
            int o = cntD[idx]; cntD[idx] = rD; rD += o;
            o = cntS[idx];     cntS[idx] = rS; rS += o;
        }
    }
}

// ---------------- phase C: scatter edges into dst-buckets (pairs) and src-buckets (srcl) ----------------
__global__ __launch_bounds__(256) void k_scatter(const int* __restrict__ src, const int* __restrict__ dst,
                                                 const int* __restrict__ cntD, const int* __restrict__ cntS,
                                                 int2* __restrict__ pairs, int* __restrict__ srcl, int E){
    __shared__ unsigned oD[1024], oS[1024];
    for (int i=threadIdx.x; i<1024; i+=256){
        oD[i] = (unsigned)cntD[blockIdx.x*1024 + i];
        oS[i] = (unsigned)cntS[blockIdx.x*1024 + i];
    }
    __syncthreads();
    int chunk = (E + GPART - 1)/GPART;
    int start = blockIdx.x*chunk;
    int end   = min(E, start + chunk);
    for (int e = start + threadIdx.x; e < end; e += 256){
        int s = src[e], d = dst[e];
        unsigned pD = atomicAdd(&oD[d/BPB], 1u);
        pairs[pD] = make_int2(s, d);
        unsigned pS = atomicAdd(&oS[s/BPB], 1u);
        srcl[pS] = s;
    }
}

// ---------------- out-degree per node from src-buckets -> sn ----------------
__global__ __launch_bounds__(256) void k_outdeg(const int* __restrict__ srcl, const int* __restrict__ bstartS,
                                                float* __restrict__ sn, int N){
    __shared__ int c[BPB];
    int b = blockIdx.x;
    if (threadIdx.x < BPB) c[threadIdx.x] = 0;
    __syncthreads();
    int s0 = bstartS[b], s1 = bstartS[b+1];
    int base = b*BPB;
    for (int i = s0 + threadIdx.x; i < s1; i += 256)
        atomicAdd(&c[srcl[i] - base], 1);
    __syncthreads();
    int node = base + threadIdx.x;
    if (threadIdx.x < BPB && node < N)
        sn[node] = rsqrtf((float)max(c[threadIdx.x], 1));
}

// ---------------- graph segment starts (n2g sorted) ----------------
__global__ __launch_bounds__(256) void k_gstart(const int* __restrict__ n2g, int* __restrict__ gstart, int N){
    int n = blockIdx.x*256 + threadIdx.x;
    if (n < N){
        int g  = n2g[n];
        int gp = (n == 0) ? -1 : n2g[n-1];
        if (gp != g){
            for (int gg = gp+1; gg <= g; ++gg) gstart[gg] = n;
        }
        if (n == N-1){
            for (int gg = g+1; gg <= NG; ++gg) gstart[gg] = N;
        }
    }
}

// ---------------- GEMM1 (MFMA bf16): h[N,64] fp32 = x @ W1 (unscaled) ----------------
__global__ __launch_bounds__(256) void k_gemm1(const float* __restrict__ x, const short* __restrict__ Wb,
                                               float* __restrict__ h, int N){
    const int lane = threadIdx.x & 63;
    const int wid  = threadIdx.x >> 6;
    const int rowBase = blockIdx.x*64 + wid*16;
    const int mrow = lane & 15;
    const int s    = lane >> 4;

    int row  = rowBase + mrow;
    int rowc = (row < N) ? row : (N-1);

    const float4*  __restrict__ xv = (const float4*)x;
    const bf16x8*  __restrict__ wv = (const bf16x8*)Wb;

    f32x4 acc0 = {0.f,0.f,0.f,0.f};
    f32x4 acc1 = {0.f,0.f,0.f,0.f};
    f32x4 acc2 = {0.f,0.f,0.f,0.f};
    f32x4 acc3 = {0.f,0.f,0.f,0.f};

    const float4* xrow = xv + (size_t)rowc*128 + s*2;
    #pragma unroll 4
    for (int g=0; g<16; g++){
        float4 a0 = xrow[g*8 + 0];
        float4 a1 = xrow[g*8 + 1];
        bf16x8 af;
        af[0]=(short)f2bf(a0.x); af[1]=(short)f2bf(a0.y); af[2]=(short)f2bf(a0.z); af[3]=(short)f2bf(a0.w);
        af[4]=(short)f2bf(a1.x); af[5]=(short)f2bf(a1.y); af[6]=(short)f2bf(a1.z); af[7]=(short)f2bf(a1.w);
        int bbase = (g*4 + s)*64 + mrow;
        bf16x8 b0 = wv[bbase     ];
        bf16x8 b1 = wv[bbase + 16];
        bf16x8 b2 = wv[bbase + 32];
        bf16x8 b3 = wv[bbase + 48];
        acc0 = __builtin_amdgcn_mfma_f32_16x16x32_bf16(af, b0, acc0, 0, 0, 0);
        acc1 = __builtin_amdgcn_mfma_f32_16x16x32_bf16(af, b1, acc1, 0, 0, 0);
        acc2 = __builtin_amdgcn_mfma_f32_16x16x32_bf16(af, b2, acc2, 0, 0, 0);
        acc3 = __builtin_amdgcn_mfma_f32_16x16x32_bf16(af, b3, acc3, 0, 0, 0);
    }

    int orow = rowBase + s*4;
    #pragma unroll
    for (int q=0; q<4; q++){
        int rr = orow + q;
        if (rr < N){
            float* hp = h + ((size_t)rr<<6) + mrow;
            hp[ 0] = acc0[q];
            hp[16] = acc1[q];
            hp[32] = acc2[q];
            hp[48] = acc3[q];
        }
    }
}

// ---------------- scale h by sn, convert to bf16 ----------------
__global__ __launch_bounds__(256) void k_scaleh(const float* __restrict__ h, const float* __restrict__ sn,
                                                unsigned short* __restrict__ hb, int N){
    int i = blockIdx.x*256 + threadIdx.x;
    if (i < N*16){
        int row = i >> 4, seg = i & 15;
        float s = sn[row];
        float4 v = *(const float4*)(h + ((size_t)row<<6) + (seg<<2));
        unsigned lo = (unsigned)f2bf(v.x*s) | ((unsigned)f2bf(v.y*s) << 16);
        unsigned hi = (unsigned)f2bf(v.z*s) | ((unsigned)f2bf(v.w*s) << 16);
        uint2 r; r.x = lo; r.y = hi;
        *(uint2*)(hb + ((size_t)row<<6) + (seg<<2)) = r;
    }
}

// ---------------- phase D: per-bucket aggregate + relu/norm + GEMM2(64->10) ----------------
// block = bucket. LDS acc[98][65] fp32; 16 lanes x 4ch per edge, 16 edges per block-iter.
__global__ __launch_bounds__(256) void k_agg(const int2* __restrict__ pairs, const int* __restrict__ bstartD,
                                             const unsigned short* __restrict__ hb,
                                             const float* __restrict__ sn, const float* __restrict__ b1,
                                             const float* __restrict__ W2, const int* __restrict__ n2g,
                                             float* __restrict__ h2, float2* __restrict__ dg, int N){
    __shared__ float acc[BPB*65];
    __shared__ int cntL[BPB];
    __shared__ float w2s[640];
    __shared__ float b1s[64];
    int tid = threadIdx.x;
    for (int i=tid; i<BPB*65; i+=256) acc[i] = 0.f;
    if (tid < BPB) cntL[tid] = 0;
    if (tid < 64)  b1s[tid] = b1[tid];
    for (int i=tid; i<640; i+=256){ int cc = i>>6, rr = i&63; w2s[i] = W2[rr*10 + cc]; }
    __syncthreads();

    int b = blockIdx.x;
    int nodeBase = b*BPB;
    int eb = bstartD[b], ee = bstartD[b+1];
    int lane = tid & 63, wid = tid >> 6;
    int sub = lane >> 4;        // edge-within-wave (0..3)
    int q   = lane & 15;        // 16 lanes per edge
    int cb  = q << 2;           // 4 channels per lane

    for (int it = eb; it < ee; it += 16){
        int e = it + wid*4 + sub;
        if (e < ee){
            int2 pr = pairs[e];
            int dl = pr.y - nodeBase;
            const uint2* hp = (const uint2*)(hb + ((size_t)pr.x << 6));
            uint2 v = hp[q];
            float f0 = __uint_as_float((v.x & 0xffffu) << 16);
            float f1 = __uint_as_float(v.x & 0xffff0000u);
            float f2 = __uint_as_float((v.y & 0xffffu) << 16);
            float f3 = __uint_as_float(v.y & 0xffff0000u);
            float* ap = acc + dl*65 + cb;
            atomicAdd(ap+0, f0);
            atomicAdd(ap+1, f1);
            atomicAdd(ap+2, f2);
            atomicAdd(ap+3, f3);
            if (q == 0) atomicAdd(&cntL[dl], 1);
        }
    }
    __syncthreads();

    for (int nl = wid; nl < BPB; nl += 4){
        int node = nodeBase + nl;
        if (node >= N) break;
        float v = acc[nl*65 + lane];
        float dnv = rsqrtf((float)max(cntL[nl], 1));
        float a = fmaxf(fmaf(v, dnv, b1s[lane]), 0.f) * sn[node];
        float s[10];
        #pragma unroll
        for (int c=0;c<10;c++){
            float t = a * w2s[(c<<6) + lane];
            t += __shfl_xor(t, 1);
            t += __shfl_xor(t, 2);
            t += __shfl_xor(t, 4);
            t += __shfl_xor(t, 8);
            t += __shfl_xor(t, 16);
            t += __shfl_xor(t, 32);
            s[c] = t;
        }
        float o = s[0];
        #pragma unroll
        for (int c=1;c<10;c++) o = (lane == c) ? s[c] : o;
        if (lane < 10) h2[node*10 + lane] = o;
        if (lane == 0){
            float2 p; p.x = dnv; p.y = __uint_as_float((unsigned)n2g[node]);
            dg[node] = p;
        }
    }
}

// ---------------- fused SpMM2 + pooling ----------------
__global__ __launch_bounds__(256) void k_pool(const int* __restrict__ esrc, const int* __restrict__ edst,
                                              const float2* __restrict__ dg,
                                              const float* __restrict__ h2, float* __restrict__ pooled, int E){
    __shared__ float accS[NG*10];
    for (int i=threadIdx.x; i<NG*10; i+=256) accS[i] = 0.f;
    __syncthreads();
    for (int e = blockIdx.x*256 + threadIdx.x; e < E; e += gridDim.x*256){
        int d = edst[e]; int sI = esrc[e];
        float2 t = dg[d];
        float w = t.x;
        int g = (int)__float_as_uint(t.y);
        const float2* hp = (const float2*)(h2 + (size_t)sI*10);
        #pragma unroll
        for (int qq=0;qq<5;qq++){
            float2 v = hp[qq];
            atomicAdd(&accS[g*10 + 2*qq],     w*v.x);
            atomicAdd(&accS[g*10 + 2*qq + 1], w*v.y);
        }
    }
    __syncthreads();
    for (int i=threadIdx.x; i<NG*10; i+=256) atomicAdd(&pooled[i], accS[i]);
}

// ---------------- final ----------------
__global__ void k_out(const float* __restrict__ pooled, const int* __restrict__ gstart,
                      const float* __restrict__ b2, float* __restrict__ out){
    int i = blockIdx.x*blockDim.x + threadIdx.x;
    if (i < NG*10){
        int g = i/10, c = i - g*10;
        float cnt = (float)max(gstart[g+1] - gstart[g], 1);
        out[i] = pooled[i]/cnt + b2[c];
    }
}

extern "C" void kernel_launch(void* const* d_in, const int* in_sizes, int n_in,
                              void* d_out, int out_size, void* d_ws, size_t ws_size,
                              hipStream_t stream) {
    const float* x    = (const float*)d_in[0];
    const int*   esrc = (const int*)d_in[1];
    const int*   edst = (const int*)d_in[2];
    const int*   n2g  = (const int*)d_in[3];
    const float* W1   = (const float*)d_in[5];
    const float* b1   = (const float*)d_in[6];
    const float* W2   = (const float*)d_in[7];
    const float* b2   = (const float*)d_in[8];
    float* out = (float*)d_out;
    const int N = in_sizes[3];
    const int E = in_sizes[1];

    char* ws = (char*)d_ws;
    size_t off = 0;
    auto alloc = [&](size_t bytes) -> void* {
        void* p = ws + off;
        off = (off + bytes + 255) & ~(size_t)255;
        return p;
    };
    float* pooled  = (float*)alloc(NG*10*4);
    int*   cntD    = (int*)alloc((size_t)GPART*1024*4);
    int*   cntS    = (int*)alloc((size_t)GPART*1024*4);
    int*   totD    = (int*)alloc(1024*4);
    int*   totS    = (int*)alloc(1024*4);
    int*   bstartD = (int*)alloc((NBUK+1)*4);
    int*   bstartS = (int*)alloc((NBUK+1)*4);
    int2*  pairs   = (int2*)alloc((size_t)E*8);
    int*   srcl    = (int*)alloc((size_t)E*4);
    float* sn      = (float*)alloc((size_t)N*4);
    float2* dg     = (float2*)alloc((size_t)N*8);
    int*   gstart  = (int*)alloc((size_t)(NG+1)*4);
    short* Wb      = (short*)alloc((size_t)512*64*2);
    float* h       = (float*)alloc((size_t)N*64*4);
    unsigned short* hb = (unsigned short*)alloc((size_t)N*64*2);
    float* h2      = (float*)alloc((size_t)N*10*4);

    k_zero<<<dim3(3), dim3(256), 0, stream>>>(pooled, NG*10);
    k_prepw<<<dim3(128), dim3(256), 0, stream>>>(W1, Wb);

    k_count<<<dim3(GPART), dim3(256), 0, stream>>>(esrc, edst, cntD, cntS, E);
    k_scanA<<<dim3(4), dim3(256), 0, stream>>>(cntD, cntS, totD, totS);
    k_scanB<<<dim3(1), dim3(1024), 0, stream>>>(totD, totS, bstartD, bstartS);
    k_scanC<<<dim3(4), dim3(256), 0, stream>>>(cntD, cntS, bstartD, bstartS);
    k_scatter<<<dim3(GPART), dim3(256), 0, stream>>>(esrc, edst, cntD, cntS, pairs, srcl, E);
    k_outdeg<<<dim3(NBUK), dim3(256), 0, stream>>>(srcl, bstartS, sn, N);
    k_gstart<<<dim3((N+255)/256), dim3(256), 0, stream>>>(n2g, gstart, N);

    k_gemm1<<<dim3((N+63)/64), dim3(256), 0, stream>>>(x, Wb, h, N);
    k_scaleh<<<dim3((N*16+255)/256), dim3(256), 0, stream>>>(h, sn, hb, N);

    k_agg<<<dim3(NBUK), dim3(256), 0, stream>>>(pairs, bstartD, hb, sn, b1, W2, n2g, h2, dg, N);
    k_pool<<<dim3(512), dim3(256), 0, stream>>>(esrc, edst, dg, h2, pooled, E);
    k_out<<<dim3(3), dim3(256), 0, stream>>>(pooled, gstart, b2, out);
}

// Round 8
// 314.923 us; speedup vs baseline: 2.6660x; 2.6660x over previous
//
#include <hip/hip_runtime.h>

#define NN 100000
#define NE 1600000
#define NG 64
#define BPB  50       // nodes per bucket
#define NBUK 2000     // NN / BPB exactly
#define NBUK2 2048    // padded bucket array size
#define ECAP 1120     // per-bucket staged edge capacity (mean 800, max ~910 at +4 sigma)
#define GPART 128     // partition grid

using bf16x8 = __attribute__((ext_vector_type(8))) short;
using f32x4  = __attribute__((ext_vector_type(4))) float;

__device__ inline unsigned short f2bf(float f){
    union { float f; unsigned u; } v; v.f = f;
    unsigned r = (v.u + 0x7FFFu + ((v.u >> 16) & 1u)) >> 16;
    return (unsigned short)r;
}

// ---------------- zero (pooled only) ----------------
__global__ void k_zero(float* p, int n){
    int i = blockIdx.x*blockDim.x + threadIdx.x;
    if (i < n) p[i] = 0.f;
}

// ---------------- W1 -> bf16, fragment-ordered ----------------
__global__ __launch_bounds__(256) void k_prepw(const float* __restrict__ W1, short* __restrict__ Wb){
    int i = blockIdx.x*256 + threadIdx.x;
    if (i < 512*64){
        int k = i >> 6, c = i & 63;
        int g = k >> 5, r = k & 31, s = r >> 3, j = r & 7;
        Wb[(((g*4+s)*64 + c) << 3) + j] = (short)f2bf(W1[i]);
    }
}

// ---------------- phase A: per-block bucket histograms (LDS atomics) ----------------
__global__ __launch_bounds__(256) void k_count(const int* __restrict__ src, const int* __restrict__ dst,
                                               int* __restrict__ cntD, int* __restrict__ cntS, int E){
    __shared__ int hD[NBUK2], hS[NBUK2];
    for (int i=threadIdx.x; i<NBUK2; i+=256){ hD[i]=0; hS[i]=0; }
    __syncthreads();
    int chunk = (E + GPART - 1)/GPART;
    int start = blockIdx.x*chunk;
    int end   = min(E, start + chunk);
    for (int e = start + threadIdx.x; e < end; e += 256){
        atomicAdd(&hS[src[e]/BPB], 1);
        atomicAdd(&hD[dst[e]/BPB], 1);
    }
    __syncthreads();
    for (int i=threadIdx.x; i<NBUK2; i+=256){
        cntD[blockIdx.x*NBUK2 + i] = hD[i];
        cntS[blockIdx.x*NBUK2 + i] = hS[i];
    }
}

// ---------------- scan A: per-bucket totals ----------------
__global__ __launch_bounds__(256) void k_scanA(const int* __restrict__ cntD, const int* __restrict__ cntS,
                                               int* __restrict__ totD, int* __restrict__ totS){
    int t = blockIdx.x*256 + threadIdx.x;   // grid 8 -> t in [0,2048)
    int sD=0, sS=0;
    for (int b=0;b<GPART;b++){ sD += cntD[b*NBUK2+t]; sS += cntS[b*NBUK2+t]; }
    totD[t]=sD; totS[t]=sS;
}

// ---------------- scan B: exclusive scan of 2048 bucket totals (1024 thr, 2/thread) ----------------
__global__ __launch_bounds__(1024) void k_scanB(const int* __restrict__ totD, const int* __restrict__ totS,
                                                int* __restrict__ bstartD, int* __restrict__ bstartS){
    __shared__ int sd[1024];
    int t = threadIdx.x;
    {
        int v0 = totD[2*t], v1 = totD[2*t+1];
        sd[t] = v0+v1; __syncthreads();
        for (int off=1; off<1024; off<<=1){
            int tv = (t >= off) ? sd[t-off] : 0;
            __syncthreads();
            sd[t] += tv;
            __syncthreads();
        }
        int excl = sd[t] - v0 - v1;
        if (2*t   <= NBUK) bstartD[2*t]   = excl;
        if (2*t+1 <= NBUK) bstartD[2*t+1] = excl + v0;
        __syncthreads();
    }
    {
        int v0 = totS[2*t], v1 = totS[2*t+1];
        sd[t] = v0+v1; __syncthreads();
        for (int off=1; off<1024; off<<=1){
            int tv = (t >= off) ? sd[t-off] : 0;
            __syncthreads();
            sd[t] += tv;
            __syncthreads();
        }
        int excl = sd[t] - v0 - v1;
        if (2*t   <= NBUK) bstartS[2*t]   = excl;
        if (2*t+1 <= NBUK) bstartS[2*t+1] = excl + v0;
    }
}

// ---------------- scan C: cnt arrays -> absolute per-(block,bucket) starts ----------------
__global__ __launch_bounds__(256) void k_scanC(int* __restrict__ cntD, int* __restrict__ cntS,
                                               const int* __restrict__ bstartD, const int* __restrict__ bstartS){
    int t = blockIdx.x*256 + threadIdx.x;
    if (t < NBUK){
        int rD = bstartD[t], rS = bstartS[t];
        for (int b=0;b<GPART;b++){
            int idx = b*NBUK2 + t;
            int o = cntD[idx]; cntD[idx] = rD; rD += o;
            o = cntS[idx];     cntS[idx] = rS; rS += o;
        }
    }
}

// ---------------- phase C: scatter edges into dst-buckets (pairs) and src-buckets (srcl) ----------------
__global__ __launch_bounds__(256) void k_scatter(const int* __restrict__ src, const int* __restrict__ dst,
                                                 const int* __restrict__ cntD, const int* __restrict__ cntS,
                                                 int2* __restrict__ pairs, int* __restrict__ srcl, int E){
    __shared__ unsigned oD[NBUK2], oS[NBUK2];
    for (int i=threadIdx.x; i<NBUK2; i+=256){
        oD[i] = (unsigned)cntD[blockIdx.x*NBUK2 + i];
        oS[i] = (unsigned)cntS[blockIdx.x*NBUK2 + i];
    }
    __syncthreads();
    int chunk = (E + GPART - 1)/GPART;
    int start = blockIdx.x*chunk;
    int end   = min(E, start + chunk);
    for (int e = start + threadIdx.x; e < end; e += 256){
        int s = src[e], d = dst[e];
        unsigned pD = atomicAdd(&oD[d/BPB], 1u);
        pairs[pD] = make_int2(s, d);
        unsigned pS = atomicAdd(&oS[s/BPB], 1u);
        srcl[pS] = s;
    }
}

// ---------------- out-degree per node from src-buckets -> sn ----------------
__global__ __launch_bounds__(256) void k_outdeg(const int* __restrict__ srcl, const int* __restrict__ bstartS,
                                                float* __restrict__ sn, int N){
    __shared__ int c[BPB];
    int b = blockIdx.x;
    if (threadIdx.x < BPB) c[threadIdx.x] = 0;
    __syncthreads();
    int s0 = bstartS[b], s1 = bstartS[b+1];
    int base = b*BPB;
    for (int i = s0 + threadIdx.x; i < s1; i += 256)
        atomicAdd(&c[srcl[i] - base], 1);
    __syncthreads();
    int node = base + threadIdx.x;
    if (threadIdx.x < BPB && node < N)
        sn[node] = rsqrtf((float)max(c[threadIdx.x], 1));
}

// ---------------- graph segment starts (n2g sorted) ----------------
__global__ __launch_bounds__(256) void k_gstart(const int* __restrict__ n2g, int* __restrict__ gstart, int N){
    int n = blockIdx.x*256 + threadIdx.x;
    if (n < N){
        int g  = n2g[n];
        int gp = (n == 0) ? -1 : n2g[n-1];
        if (gp != g){
            for (int gg = gp+1; gg <= g; ++gg) gstart[gg] = n;
        }
        if (n == N-1){
            for (int gg = g+1; gg <= NG; ++gg) gstart[gg] = N;
        }
    }
}

// ---------------- GEMM1 (MFMA bf16): hb[N,64](bf16) = (x @ W1) * src_norm ----------------
__global__ __launch_bounds__(256) void k_gemm1(const float* __restrict__ x, const short* __restrict__ Wb,
                                               const float* __restrict__ sn, unsigned short* __restrict__ hb, int N){
    const int lane = threadIdx.x & 63;
    const int wid  = threadIdx.x >> 6;
    const int rowBase = blockIdx.x*64 + wid*16;
    const int mrow = lane & 15;
    const int s    = lane >> 4;

    int row  = rowBase + mrow;
    int rowc = (row < N) ? row : (N-1);

    const float4*  __restrict__ xv = (const float4*)x;
    const bf16x8*  __restrict__ wv = (const bf16x8*)Wb;

    f32x4 acc0 = {0.f,0.f,0.f,0.f};
    f32x4 acc1 = {0.f,0.f,0.f,0.f};
    f32x4 acc2 = {0.f,0.f,0.f,0.f};
    f32x4 acc3 = {0.f,0.f,0.f,0.f};

    const float4* xrow = xv + (size_t)rowc*128 + s*2;
    #pragma unroll 4
    for (int g=0; g<16; g++){
        float4 a0 = xrow[g*8 + 0];
        float4 a1 = xrow[g*8 + 1];
        bf16x8 af;
        af[0]=(short)f2bf(a0.x); af[1]=(short)f2bf(a0.y); af[2]=(short)f2bf(a0.z); af[3]=(short)f2bf(a0.w);
        af[4]=(short)f2bf(a1.x); af[5]=(short)f2bf(a1.y); af[6]=(short)f2bf(a1.z); af[7]=(short)f2bf(a1.w);
        int bbase = (g*4 + s)*64 + mrow;
        bf16x8 b0 = wv[bbase     ];
        bf16x8 b1 = wv[bbase + 16];
        bf16x8 b2 = wv[bbase + 32];
        bf16x8 b3 = wv[bbase + 48];
        acc0 = __builtin_amdgcn_mfma_f32_16x16x32_bf16(af, b0, acc0, 0, 0, 0);
        acc1 = __builtin_amdgcn_mfma_f32_16x16x32_bf16(af, b1, acc1, 0, 0, 0);
        acc2 = __builtin_amdgcn_mfma_f32_16x16x32_bf16(af, b2, acc2, 0, 0, 0);
        acc3 = __builtin_amdgcn_mfma_f32_16x16x32_bf16(af, b3, acc3, 0, 0, 0);
    }

    int orow = rowBase + s*4;
    #pragma unroll
    for (int q=0; q<4; q++){
        int rr = orow + q;
        if (rr < N){
            float scale = sn[rr];
            unsigned short* hp = hb + ((size_t)rr<<6) + mrow;
            hp[ 0] = f2bf(acc0[q] * scale);
            hp[16] = f2bf(acc1[q] * scale);
            hp[32] = f2bf(acc2[q] * scale);
            hp[48] = f2bf(acc3[q] * scale);
        }
    }
}

// ---------------- phase D: per-bucket CSR-in-LDS + register-accum gather + GEMM2 ----------------
// block = bucket of 50 dst nodes. Build per-node src lists in LDS, then wave-per-node
// dual-edge gather (round-4 spmm pattern, no atomics in hot loop).
// Lane layout: half = lane>>5 (edge parity), c2 = lane&31 (channel pair 2*c2, 2*c2+1).
// Lanes l and l+32 cover the SAME channels; after the xor-32 accumulator combine the
// xor-1..16 reduction within one half already yields the full 64-channel dot product.
__global__ __launch_bounds__(256) void k_agg(const int2* __restrict__ pairs, const int* __restrict__ bstartD,
                                             const unsigned short* __restrict__ hb,
                                             const float* __restrict__ sn, const float* __restrict__ b1,
                                             const float* __restrict__ W2, const int* __restrict__ n2g,
                                             float* __restrict__ h2, float2* __restrict__ dg, int N){
    __shared__ int lsrc[ECAP];
    __shared__ int lcnt[BPB];
    __shared__ int lstart[BPB+1];
    __shared__ unsigned lofs[BPB];
    __shared__ float w2s[640];
    __shared__ float b1s[64];
    int tid = threadIdx.x;
    if (tid < BPB) lcnt[tid] = 0;
    if (tid < 64)  b1s[tid] = b1[tid];
    for (int i=tid; i<640; i+=256){ int cc = i>>6, rr = i&63; w2s[i] = W2[rr*10 + cc]; }
    __syncthreads();

    int b = blockIdx.x;
    int nodeBase = b*BPB;
    int eb = bstartD[b], ee = bstartD[b+1];
    int ne = ee - eb;

    // pass 1: count per-node in-degree
    for (int i = tid; i < ne; i += 256){
        int2 pr = pairs[eb + i];
        atomicAdd(&lcnt[pr.y - nodeBase], 1);
    }
    __syncthreads();
    // serial scan over 50 entries
    if (tid == 0){
        int run = 0;
        for (int k=0;k<BPB;k++){ lstart[k] = run; lofs[k] = (unsigned)run; run += lcnt[k]; }
        lstart[BPB] = run;
    }
    __syncthreads();
    // pass 2: scatter src ids into per-node lists
    for (int i = tid; i < ne; i += 256){
        int2 pr = pairs[eb + i];
        unsigned pos = atomicAdd(&lofs[pr.y - nodeBase], 1u);
        lsrc[pos < ECAP ? pos : ECAP-1] = pr.x;
    }
    __syncthreads();

    // phase 2: wave-per-node gather, register accumulation
    int lane = tid & 63, wid = tid >> 6;
    int half = lane >> 5;
    int c2   = lane & 31;

    for (int nl = wid; nl < BPB; nl += 4){
        int node = nodeBase + nl;
        if (node >= N) break;
        int s0 = lstart[nl];
        int m  = lstart[nl+1] - s0;

        float accx = 0.f, accy = 0.f;
        int j = 0;
        for (; j + 4 <= m; j += 4){
            int sa = lsrc[s0 + j + half];
            int sb = lsrc[s0 + j + 2 + half];
            unsigned va = *(const unsigned*)(hb + ((size_t)sa<<6) + (c2<<1));
            unsigned vb = *(const unsigned*)(hb + ((size_t)sb<<6) + (c2<<1));
            accx += __uint_as_float((va & 0xffffu) << 16);
            accy += __uint_as_float(va & 0xffff0000u);
            accx += __uint_as_float((vb & 0xffffu) << 16);
            accy += __uint_as_float(vb & 0xffff0000u);
        }
        for (; j < m; j += 2){
            int idx = j + half;
            int idxc = (idx < m) ? idx : (m-1);
            int sa = lsrc[s0 + idxc];
            unsigned va = *(const unsigned*)(hb + ((size_t)sa<<6) + (c2<<1));
            if (idx < m){
                accx += __uint_as_float((va & 0xffffu) << 16);
                accy += __uint_as_float(va & 0xffff0000u);
            }
        }
        accx += __shfl_xor(accx, 32);
        accy += __shfl_xor(accy, 32);

        float dnv = rsqrtf((float)max(m, 1));
        float snv = sn[node];
        float ax = fmaxf(fmaf(accx, dnv, b1s[c2<<1]), 0.f) * snv;
        float ay = fmaxf(fmaf(accy, dnv, b1s[(c2<<1)+1]), 0.f) * snv;

        float s[10];
        #pragma unroll
        for (int c=0;c<10;c++){
            float t = fmaf(ax, w2s[(c<<6) + (c2<<1)], ay * w2s[(c<<6) + (c2<<1) + 1]);
            t += __shfl_xor(t, 1);
            t += __shfl_xor(t, 2);
            t += __shfl_xor(t, 4);
            t += __shfl_xor(t, 8);
            t += __shfl_xor(t, 16);
            s[c] = t;   // full 64-channel dot product (halves are duplicates — no xor-32!)
        }
        float o = s[0];
        #pragma unroll
        for (int c=1;c<10;c++) o = (lane == c) ? s[c] : o;
        if (lane < 10) h2[node*10 + lane] = o;
        if (lane == 0){
            float2 p; p.x = dnv; p.y = __uint_as_float((unsigned)n2g[node]);
            dg[node] = p;
        }
    }
}

// ---------------- fused SpMM2 + pooling ----------------
__global__ __launch_bounds__(256) void k_pool(const int* __restrict__ esrc, const int* __restrict__ edst,
                                              const float2* __restrict__ dg,
                                              const float* __restrict__ h2, float* __restrict__ pooled, int E){
    __shared__ float accS[NG*10];
    for (int i=threadIdx.x; i<NG*10; i+=256) accS[i] = 0.f;
    __syncthreads();
    for (int e = blockIdx.x*256 + threadIdx.x; e < E; e += gridDim.x*256){
        int d = edst[e]; int sI = esrc[e];
        float2 t = dg[d];
        float w = t.x;
        int g = (int)__float_as_uint(t.y);
        const float2* hp = (const float2*)(h2 + (size_t)sI*10);
        #pragma unroll
        for (int qq=0;qq<5;qq++){
            float2 v = hp[qq];
            atomicAdd(&accS[g*10 + 2*qq],     w*v.x);
            atomicAdd(&accS[g*10 + 2*qq + 1], w*v.y);
        }
    }
    __syncthreads();
    for (int i=threadIdx.x; i<NG*10; i+=256) atomicAdd(&pooled[i], accS[i]);
}

// ---------------- final ----------------
__global__ void k_out(const float* __restrict__ pooled, const int* __restrict__ gstart,
                      const float* __restrict__ b2, float* __restrict__ out){
    int i = blockIdx.x*blockDim.x + threadIdx.x;
    if (i < NG*10){
        int g = i/10, c = i - g*10;
        float cnt = (float)max(gstart[g+1] - gstart[g], 1);
        out[i] = pooled[i]/cnt + b2[c];
    }
}

extern "C" void kernel_launch(void* const* d_in, const int* in_sizes, int n_in,
                              void* d_out, int out_size, void* d_ws, size_t ws_size,
                              hipStream_t stream) {
    const float* x    = (const float*)d_in[0];
    const int*   esrc = (const int*)d_in[1];
    const int*   edst = (const int*)d_in[2];
    const int*   n2g  = (const int*)d_in[3];
    const float* W1   = (const float*)d_in[5];
    const float* b1   = (const float*)d_in[6];
    const float* W2   = (const float*)d_in[7];
    const float* b2   = (const float*)d_in[8];
    float* out = (float*)d_out;
    const int N = in_sizes[3];
    const int E = in_sizes[1];

    char* ws = (char*)d_ws;
    size_t off = 0;
    auto alloc = [&](size_t bytes) -> void* {
        void* p = ws + off;
        off = (off + bytes + 255) & ~(size_t)255;
        return p;
    };
    float* pooled  = (float*)alloc(NG*10*4);
    int*   cntD    = (int*)alloc((size_t)GPART*NBUK2*4);
    int*   cntS    = (int*)alloc((size_t)GPART*NBUK2*4);
    int*   totD    = (int*)alloc(NBUK2*4);
    int*   totS    = (int*)alloc(NBUK2*4);
    int*   bstartD = (int*)alloc((NBUK+1)*4);
    int*   bstartS = (int*)alloc((NBUK+1)*4);
    int2*  pairs   = (int2*)alloc((size_t)E*8);
    int*   srcl    = (int*)alloc((size_t)E*4);
    float* sn      = (float*)alloc((size_t)N*4);
    float2* dg     = (float2*)alloc((size_t)N*8);
    int*   gstart  = (int*)alloc((size_t)(NG+1)*4);
    short* Wb      = (short*)alloc((size_t)512*64*2);
    unsigned short* hb = (unsigned short*)alloc((size_t)N*64*2);
    float* h2      = (float*)alloc((size_t)N*10*4);

    k_zero<<<dim3(3), dim3(256), 0, stream>>>(pooled, NG*10);
    k_prepw<<<dim3(128), dim3(256), 0, stream>>>(W1, Wb);

    k_count<<<dim3(GPART), dim3(256), 0, stream>>>(esrc, edst, cntD, cntS, E);
    k_scanA<<<dim3(8), dim3(256), 0, stream>>>(cntD, cntS, totD, totS);
    k_scanB<<<dim3(1), dim3(1024), 0, stream>>>(totD, totS, bstartD, bstartS);
    k_scanC<<<dim3(8), dim3(256), 0, stream>>>(cntD, cntS, bstartD, bstartS);
    k_scatter<<<dim3(GPART), dim3(256), 0, stream>>>(esrc, edst, cntD, cntS, pairs, srcl, E);
    k_outdeg<<<dim3(NBUK), dim3(256), 0, stream>>>(srcl, bstartS, sn, N);
    k_gstart<<<dim3((N+255)/256), dim3(256), 0, stream>>>(n2g, gstart, N);

    k_gemm1<<<dim3((N+63)/64), dim3(256), 0, stream>>>(x, Wb, sn, hb, N);

    k_agg<<<dim3(NBUK), dim3(256), 0, stream>>>(pairs, bstartD, hb, sn, b1, W2, n2g, h2, dg, N);
    k_pool<<<dim3(512), dim3(256), 0, stream>>>(esrc, edst, dg, h2, pooled, E);
    k_out<<<dim3(3), dim3(256), 0, stream>>>(pooled, gstart, b2, out);
}